// Round 1
// baseline (778.695 us; speedup 1.0000x reference)
//
#include <hip/hip_runtime.h>
#include <cstdint>
#include <cstddef>

typedef unsigned short ushort;
typedef __attribute__((ext_vector_type(8))) short short8;
typedef __attribute__((ext_vector_type(8))) unsigned short ushort8;
typedef __attribute__((ext_vector_type(4))) float float4v;

#define DM    2048
#define INNERC 4096
#define LSEQ  4096
#define NBATCH 2
#define MROWS 8192      // NBATCH*LSEQ
#define NHH   64
#define HDD   64
#define NCHUNK 32
#define CHLEN  128
#define CROWS 8         // conv rows per block

__device__ __forceinline__ float bf2f(ushort u) {
    return __uint_as_float(((unsigned int)u) << 16);
}
__device__ __forceinline__ ushort f2bf(float f) {
    unsigned int u = __float_as_uint(f);
    unsigned int r = u + 0x7FFFu + ((u >> 16) & 1u);
    return (ushort)(r >> 16);
}

// async global->LDS 16B copy. LDS dest must be wave-uniform base + lane*16.
__device__ __forceinline__ void async_cp16(const ushort* __restrict__ g, ushort* l) {
    __builtin_amdgcn_global_load_lds(
        (const __attribute__((address_space(1))) unsigned int*)g,
        (__attribute__((address_space(3))) unsigned int*)l,
        16, 0, 0);
}

// ---------------- diagnostic ----------------
__global__ void diag_kernel(float* __restrict__ out, float val) {
    if (threadIdx.x == 0 && blockIdx.x == 0) out[0] = val;
}

// ---------------- f32 -> bf16 cast ----------------
__global__ __launch_bounds__(256) void cast_bf16_kernel(
    const float* __restrict__ in, ushort* __restrict__ out, int n) {
    const int i = (blockIdx.x * 256 + threadIdx.x) * 8;
    if (i + 8 > n) return;
    const float4v a = *(const float4v*)(in + i);
    const float4v b = *(const float4v*)(in + i + 4);
    ushort8 o;
    o[0] = f2bf(a[0]); o[1] = f2bf(a[1]); o[2] = f2bf(a[2]); o[3] = f2bf(a[3]);
    o[4] = f2bf(b[0]); o[5] = f2bf(b[1]); o[6] = f2bf(b[2]); o[7] = f2bf(b[3]);
    *(ushort8*)(out + i) = o;
}

// ---------------- bf16 bt-GEMM, 256x256 tile, 8-phase counted-vmcnt ----------
// Out(M,N) = A(M,K) * W(N,K)^T.  512 threads = 8 waves (2M x 4N); per-wave
// output 128x64 -> acc[8][4].  LDS 128 KiB: A/B tiles 256x64 bf16, double-
// buffered.  Granule swizzle: 16B granule (row, q) stored at slot
// row*8 + (q ^ (row&7))  -> coalesced staging AND <=2-way bank aliasing on
// ds_read_b128 (both sides use the same involution).
// Schedule (per iteration = 2 K-tiles, 8 phases):
//   p1: read A(all 16 frags)+B[cn0-1] of tile u (buf0); stage (u+1).Bh1
//   p2: read B[cn2-3];                         stage (u+2).Ah0
//   p3: -                                      stage (u+2).Ah1
//   p4: -                                      stage (u+2).Bh0 ; vmcnt(6)
//   p5..p8: same on tile u+1 (buf1), staging (u+2).Bh1, (u+3).{Ah0,Ah1,Bh0};
//           vmcnt(6) at p8.
// Every phase: [reads|stage] -> s_barrier -> lgkmcnt(0) -> setprio(1) ->
// 16 MFMA (one C-quadrant x K=64) -> setprio(0) -> s_barrier.
// Liveness was verified phase-by-phase: each staged half-tile region is dead
// (its last reader's lgkmcnt(0) happened before a barrier that precedes the
// staging issue).  vmcnt(6) at p4/p8 lands exactly the next tile's 4 half-
// tiles while keeping 3 half-tiles in flight.  Last iteration skips OOB
// stages and drains with vmcnt(0) at p4.
// EPI: 0 = store bf16, 1 = sigmoid(acc)*Aux[off] -> bf16 (in-place ok),
//      2 = store f32.

#define PHASE_PRE() do { \
    __builtin_amdgcn_sched_barrier(0); \
    __builtin_amdgcn_s_barrier(); \
    asm volatile("s_waitcnt lgkmcnt(0)" ::: "memory"); \
    __builtin_amdgcn_sched_barrier(0); } while (0)

#define PHASE_POST() do { \
    __builtin_amdgcn_sched_barrier(0); \
    __builtin_amdgcn_s_barrier(); } while (0)

#define MFMA_Q(RL, CL) do { \
    __builtin_amdgcn_s_setprio(1); \
    _Pragma("unroll") for (int rm = 0; rm < 4; ++rm) \
    _Pragma("unroll") for (int cn = 0; cn < 2; ++cn) \
    _Pragma("unroll") for (int kk = 0; kk < 2; ++kk) \
        acc[(RL) + rm][(CL) + cn] = __builtin_amdgcn_mfma_f32_16x16x32_bf16( \
            af[(RL) + rm][kk], bf[(CL) + cn][kk], acc[(RL) + rm][(CL) + cn], 0, 0, 0); \
    __builtin_amdgcn_s_setprio(0); } while (0)

#define READ_B2(BUF, CNLO) do { \
    _Pragma("unroll") for (int cn = 0; cn < 2; ++cn) \
    _Pragma("unroll") for (int kk = 0; kk < 2; ++kk) { \
        const int rB = wn * 64 + ((CNLO) + cn) * 16 + l15; \
        bf[(CNLO) + cn][kk] = *(const short8*)&Bs[BUF][ \
            (rB * 8 + ((kk * 4 + l4) ^ swz7)) * 8]; \
    } } while (0)

template <int EPI>
__global__ __launch_bounds__(512, 2) void gemm256(
    const ushort* __restrict__ Ab, const ushort* __restrict__ Wb,
    void* __restrict__ Out, const ushort* __restrict__ Aux,
    int M, int N, int K) {
    __shared__ ushort As[2][16384];
    __shared__ ushort Bs[2][16384];

    const int tid  = threadIdx.x;
    const int lane = tid & 63;
    const int w    = tid >> 6;
    const int wm   = w >> 2;          // 0..1
    const int wn   = w & 3;           // 0..3
    const int l15  = lane & 15;
    const int l4   = lane >> 4;       // 0..3
    const int swz7 = l15 & 7;

    // XCD-aware block swizzle (nwg divisible by 8 for all our shapes)
    const int gx   = gridDim.x;
    const int nwg  = gx * gridDim.y;
    const int orig = blockIdx.y * gx + blockIdx.x;
    const int swz  = (orig & 7) * (nwg >> 3) + (orig >> 3);
    const int row0 = (swz / gx) * 256;
    const int col0 = (swz % gx) * 256;

    const int ni = K >> 7;            // iterations (2 K-tiles each)

    float4v acc[8][4];
#pragma unroll
    for (int i2 = 0; i2 < 8; i2++)
#pragma unroll
        for (int j2 = 0; j2 < 4; j2++) {
            float4v z = {0.f, 0.f, 0.f, 0.f};
            acc[i2][j2] = z;
        }

    short8 af[8][2], bf[4][2];

    // stage one half-tile (128 rows x 64 k) cooperatively (2 loads/thread)
    auto stage = [&](const ushort* __restrict__ G, int grow0, int t, ushort* dst) {
#pragma unroll
        for (int j = 0; j < 2; ++j) {
            const int c  = j * 512 + tid;
            const int r  = c >> 3;
            const int kg = (c & 7) ^ (r & 7);
            async_cp16(G + (size_t)(grow0 + r) * K + (t << 6) + kg * 8, dst + c * 8);
        }
    };

    auto readAall = [&](int b) {
#pragma unroll
        for (int rm = 0; rm < 8; ++rm)
#pragma unroll
            for (int kk = 0; kk < 2; ++kk) {
                const int rA = wm * 128 + rm * 16 + l15;
                af[rm][kk] = *(const short8*)&As[b][
                    (rA * 8 + ((kk * 4 + l4) ^ swz7)) * 8];
            }
    };

    // -------- prologue: tile0 (buf0) fully + 3 half-tiles of tile1 (buf1)
    stage(Ab, row0,       0, &As[0][0]);
    stage(Ab, row0 + 128, 0, &As[0][8192]);
    stage(Wb, col0,       0, &Bs[0][0]);
    stage(Wb, col0 + 128, 0, &Bs[0][8192]);
    stage(Ab, row0,       1, &As[1][0]);
    stage(Ab, row0 + 128, 1, &As[1][8192]);
    stage(Wb, col0,       1, &Bs[1][0]);
    asm volatile("s_waitcnt vmcnt(6)" ::: "memory");   // tile0 landed
    __builtin_amdgcn_s_barrier();

#pragma unroll 1
    for (int i = 0; i < ni; ++i) {
        const int u = 2 * i;
        const bool last = (i == ni - 1);

        // ---- p1: tile u (buf0)  Q(rm0-3, cn0-1)
        readAall(0);
        READ_B2(0, 0);
        stage(Wb, col0 + 128, u + 1, &Bs[1][8192]);     // (u+1).Bh1
        PHASE_PRE();
        MFMA_Q(0, 0);
        PHASE_POST();

        // ---- p2: Q(rm0-3, cn2-3)
        READ_B2(0, 2);
        if (!last) stage(Ab, row0, u + 2, &As[0][0]);   // (u+2).Ah0
        PHASE_PRE();
        MFMA_Q(0, 2);
        PHASE_POST();

        // ---- p3: Q(rm4-7, cn2-3)
        if (!last) stage(Ab, row0 + 128, u + 2, &As[0][8192]);
        PHASE_PRE();
        MFMA_Q(4, 2);
        PHASE_POST();

        // ---- p4: Q(rm4-7, cn0-1) + vmcnt gate (next tile = u+1 must land)
        if (!last) stage(Wb, col0, u + 2, &Bs[0][0]);
        PHASE_PRE();
        MFMA_Q(4, 0);
        __builtin_amdgcn_sched_barrier(0);
        if (last) { asm volatile("s_waitcnt vmcnt(0)" ::: "memory"); }
        else      { asm volatile("s_waitcnt vmcnt(6)" ::: "memory"); }
        __builtin_amdgcn_s_barrier();

        // ---- p5: tile u+1 (buf1)  Q(rm0-3, cn0-1)
        readAall(1);
        READ_B2(1, 0);
        if (!last) stage(Wb, col0 + 128, u + 2, &Bs[0][8192]);
        PHASE_PRE();
        MFMA_Q(0, 0);
        PHASE_POST();

        // ---- p6: Q(rm0-3, cn2-3)
        READ_B2(1, 2);
        if (!last) stage(Ab, row0, u + 3, &As[1][0]);
        PHASE_PRE();
        MFMA_Q(0, 2);
        PHASE_POST();

        // ---- p7: Q(rm4-7, cn2-3)
        if (!last) stage(Ab, row0 + 128, u + 3, &As[1][8192]);
        PHASE_PRE();
        MFMA_Q(4, 2);
        PHASE_POST();

        // ---- p8: Q(rm4-7, cn0-1) + vmcnt gate
        if (!last) stage(Wb, col0, u + 3, &Bs[1][0]);
        PHASE_PRE();
        MFMA_Q(4, 0);
        __builtin_amdgcn_sched_barrier(0);
        if (!last) { asm volatile("s_waitcnt vmcnt(6)" ::: "memory"); }
        __builtin_amdgcn_s_barrier();
    }

    // epilogue: C/D layout col = lane&15, row = (lane>>4)*4 + reg
#pragma unroll
    for (int rm = 0; rm < 8; ++rm) {
#pragma unroll
        for (int cn = 0; cn < 4; ++cn) {
            const int r0 = row0 + wm * 128 + rm * 16 + l4 * 4;
            const int cc = col0 + wn * 64 + cn * 16 + l15;
#pragma unroll
            for (int rr = 0; rr < 4; ++rr) {
                const float v = acc[rm][cn][rr];
                const size_t off = (size_t)(r0 + rr) * N + cc;
                if (EPI == 0) {
                    ((ushort*)Out)[off] = f2bf(v);
                } else if (EPI == 1) {
                    const float g = 1.0f / (1.0f + __expf(-v));
                    ((ushort*)Out)[off] = f2bf(g * bf2f(Aux[off]));
                } else {
                    ((float*)Out)[off] = v;
                }
            }
        }
    }
}

// ---------------- depthwise causal conv (K=4) + SiLU ----------------
__global__ __launch_bounds__(256) void conv_silu_kernel(
    const ushort* __restrict__ proj, const float* __restrict__ cw,
    const float* __restrict__ cb, ushort* __restrict__ X) {
    const int blk  = blockIdx.x;          // 2048 blocks
    const int half = blk & 1;
    const int tile = blk >> 1;            // 1024 tiles of 8 rows
    const int bl0  = tile * CROWS;
    const bool atStart = ((bl0 & (LSEQ - 1)) == 0);
    const int c0 = half * 2048 + threadIdx.x * 8;

    float4v w[8];
    const float4v* wp4 = (const float4v*)(cw + (size_t)c0 * 4);
#pragma unroll
    for (int t = 0; t < 8; t++) w[t] = wp4[t];
    float bias[8];
    const float4v b0 = *(const float4v*)(cb + c0);
    const float4v b1 = *(const float4v*)(cb + c0 + 4);
#pragma unroll
    for (int t = 0; t < 4; t++) { bias[t] = b0[t]; bias[t + 4] = b1[t]; }

    const size_t base = (size_t)bl0 * INNERC + c0;
    ushort8 w0, w1, w2;
    const ushort8 zz = {0, 0, 0, 0, 0, 0, 0, 0};
    if (atStart) {
        w0 = zz; w1 = zz; w2 = zz;
    } else {
        w0 = *(const ushort8*)(proj + base - 3 * (size_t)INNERC);
        w1 = *(const ushort8*)(proj + base - 2 * (size_t)INNERC);
        w2 = *(const ushort8*)(proj + base - 1 * (size_t)INNERC);
    }
#pragma unroll
    for (int r = 0; r < CROWS; r++) {
        const ushort8 cur = *(const ushort8*)(proj + base + (size_t)r * INNERC);
        ushort8 o;
#pragma unroll
        for (int j = 0; j < 8; j++) {
            const float acc = bias[j]
                + w[j][0] * bf2f(w0[j]) + w[j][1] * bf2f(w1[j])
                + w[j][2] * bf2f(w2[j]) + w[j][3] * bf2f(cur[j]);
            o[j] = f2bf(acc / (1.0f + __expf(-acc)));   // silu
        }
        *(ushort8*)(X + base + (size_t)r * INNERC) = o;
        w0 = w1; w1 = w2; w2 = cur;
    }
}

// ---------------- dt = softplus(sum_p X*dt_w + dt_b) ----------------
__global__ __launch_bounds__(64) void dt_kernel(
    const ushort* __restrict__ X, const float* __restrict__ dtw,
    const float* __restrict__ dtb, float* __restrict__ dt) {
    const int bl = blockIdx.x;
    const int h  = threadIdx.x;
    const ushort* xp = X + (size_t)bl * INNERC + h * 64;
    const float*  wp = dtw + h * 64;
    float acc = 0.0f;
#pragma unroll
    for (int p0 = 0; p0 < 64; p0 += 8) {
        const ushort8 xv = *(const ushort8*)(xp + p0);
#pragma unroll
        for (int j = 0; j < 8; j++) acc += bf2f(xv[j]) * wp[p0 + j];
    }
    const float z = acc + dtb[h];
    dt[bl * 64 + h] = (z > 20.0f) ? z : __logf(1.0f + __expf(z));
}

// ---------------- chunked diagonal scan ----------------
__global__ __launch_bounds__(256) void scan_pass1(
    const ushort* __restrict__ X, const float* __restrict__ dt,
    const float* __restrict__ A_log, const float* __restrict__ Bv,
    float* __restrict__ sumP, float* __restrict__ sumS) {
    const int task = blockIdx.x * 4 + (threadIdx.x >> 6);
    const int p  = threadIdx.x & 63;
    const int ch = task & (NCHUNK - 1);
    const int bh = task >> 5;
    const int h  = bh & 63;
    const int b  = bh >> 6;
    const float Ac = -__expf(A_log[h * 64 + p]);
    const float Bc = Bv[h * 64 + p];
    float Pr = 1.0f, s = 0.0f;
    const int bl0 = b * LSEQ + ch * CHLEN;
#pragma unroll 4
    for (int i = 0; i < CHLEN; i++) {
        const int bl   = bl0 + i;
        const float dtv = dt[bl * 64 + h];
        const float x   = bf2f(X[(size_t)bl * INNERC + h * 64 + p]);
        const float a   = __expf(dtv * Ac);
        Pr *= a;
        s = a * s + dtv * Bc * x;
    }
    sumP[(size_t)task * 64 + p] = Pr;
    sumS[(size_t)task * 64 + p] = s;
}

__global__ __launch_bounds__(64) void scan_pass2(
    const float* __restrict__ sumP, const float* __restrict__ sumS,
    float* __restrict__ carry) {
    const int bh = blockIdx.x;
    const int p  = threadIdx.x;
    float c = 0.0f;
    for (int ch = 0; ch < NCHUNK; ch++) {
        const size_t idx = ((size_t)bh * NCHUNK + ch) * 64 + p;
        carry[idx] = c;
        c = sumP[idx] * c + sumS[idx];
    }
}

__global__ __launch_bounds__(256) void scan_pass3(
    const ushort* __restrict__ X, const float* __restrict__ dt,
    const float* __restrict__ carry,
    const float* __restrict__ A_log, const float* __restrict__ Bv,
    const float* __restrict__ Cv, const float* __restrict__ Dv,
    ushort* __restrict__ Y) {
    const int task = blockIdx.x * 4 + (threadIdx.x >> 6);
    const int p  = threadIdx.x & 63;
    const int ch = task & (NCHUNK - 1);
    const int bh = task >> 5;
    const int h  = bh & 63;
    const int b  = bh >> 6;
    const float Ac = -__expf(A_log[h * 64 + p]);
    const float Bc = Bv[h * 64 + p];
    const float Cc = Cv[h * 64 + p];
    const float Dc = Dv[h * 64 + p];
    float s = carry[(size_t)task * 64 + p];
    const int bl0 = b * LSEQ + ch * CHLEN;
#pragma unroll 2
    for (int i = 0; i < CHLEN; i++) {
        const int bl = bl0 + i;
        const size_t xoff = (size_t)bl * INNERC + h * 64 + p;
        const float dtv = dt[bl * 64 + h];
        const float x   = bf2f(X[xoff]);
        const float a   = __expf(dtv * Ac);
        s = a * s + dtv * Bc * x;
        Y[xoff] = f2bf(Cc * s + Dc * x);
    }
}

// ---------------- workspace layout (bytes) ----------------
#define OFF_PROJ  ((size_t)0)            // 67,108,864 : proj -> Y -> comb
#define OFF_HID   ((size_t)67108864)     // 33,554,432 : hidden bf16
#define OFF_WB    ((size_t)100663296)    // 16,777,216 : weight bf16 (reused 3x)
#define OFF_DT    ((size_t)117440512)    //  2,097,152
#define OFF_SUMP  ((size_t)119537664)    //  1,048,576
#define OFF_SUMS  ((size_t)120586240)    //  1,048,576
#define OFF_CARRY ((size_t)121634816)    //  1,048,576
#define WS_NEEDED ((size_t)122683392)    // = 117 MiB

extern "C" void kernel_launch(void* const* d_in, const int* in_sizes, int n_in,
                              void* d_out, int out_size, void* d_ws, size_t ws_size,
                              hipStream_t stream) {
    if (ws_size < WS_NEEDED) {
        diag_kernel<<<1, 64, 0, stream>>>((float*)d_out, (float)(ws_size >> 20));
        return;
    }
    const float* hidden = (const float*)d_in[0];
    const float* w_in   = (const float*)d_in[1];
    const float* w_gate = (const float*)d_in[2];
    const float* w_out  = (const float*)d_in[3];
    const float* conv_w = (const float*)d_in[4];
    const float* conv_b = (const float*)d_in[5];
    const float* dt_w   = (const float*)d_in[6];
    const float* dt_b   = (const float*)d_in[7];
    const float* A_log  = (const float*)d_in[8];
    const float* Bv     = (const float*)d_in[9];
    const float* Cv     = (const float*)d_in[10];
    const float* Dv     = (const float*)d_in[11];

    char* ws = (char*)d_ws;
    ushort* projbuf = (ushort*)(ws + OFF_PROJ);   // proj, then Y, then comb
    ushort* hid16   = (ushort*)(ws + OFF_HID);
    ushort* wbuf    = (ushort*)(ws + OFF_WB);
    float*  dtf     = (float*)(ws + OFF_DT);
    float*  sumP    = (float*)(ws + OFF_SUMP);
    float*  sumS    = (float*)(ws + OFF_SUMS);
    float*  carry   = (float*)(ws + OFF_CARRY);
    ushort* x16     = (ushort*)d_out;             // X scratch inside d_out

    // hidden + in_proj weight casts
    cast_bf16_kernel<<<8192, 256, 0, stream>>>(hidden, hid16, MROWS * DM);
    cast_bf16_kernel<<<4096, 256, 0, stream>>>(w_in, wbuf, INNERC * DM);

    // in_proj GEMM -> proj (bf16)
    gemm256<0><<<dim3(INNERC / 256, MROWS / 256), 512, 0, stream>>>(
        hid16, wbuf, projbuf, nullptr, MROWS, INNERC, DM);

    // conv + silu -> X (in d_out), then dt
    conv_silu_kernel<<<(MROWS / CROWS) * 2, 256, 0, stream>>>(projbuf, conv_w, conv_b, x16);
    dt_kernel<<<MROWS, 64, 0, stream>>>(x16, dt_w, dt_b, dtf);

    // chunked scan; pass3 writes y into projbuf (proj dead after conv)
    scan_pass1<<<(NBATCH * NHH * NCHUNK) / 4, 256, 0, stream>>>(
        x16, dtf, A_log, Bv, sumP, sumS);
    scan_pass2<<<NBATCH * NHH, 64, 0, stream>>>(sumP, sumS, carry);
    scan_pass3<<<(NBATCH * NHH * NCHUNK) / 4, 256, 0, stream>>>(
        x16, dtf, carry, A_log, Bv, Cv, Dv, projbuf);

    // gate GEMM with fused gating: comb = sigmoid(G) * Y, in-place in projbuf
    cast_bf16_kernel<<<4096, 256, 0, stream>>>(w_gate, wbuf, INNERC * DM);
    gemm256<1><<<dim3(INNERC / 256, MROWS / 256), 512, 0, stream>>>(
        hid16, wbuf, projbuf, projbuf, MROWS, INNERC, DM);

    // output projection (f32 out) — overwrites X scratch in d_out
    cast_bf16_kernel<<<4096, 256, 0, stream>>>(w_out, wbuf, DM * INNERC);
    gemm256<2><<<dim3(DM / 256, MROWS / 256), 512, 0, stream>>>(
        projbuf, wbuf, d_out, nullptr, MROWS, DM, INNERC);
}

// Round 2
// 683.360 us; speedup vs baseline: 1.1395x; 1.1395x over previous
//
#include <hip/hip_runtime.h>
#include <cstdint>
#include <cstddef>

typedef unsigned short ushort;
typedef __attribute__((ext_vector_type(8))) short short8;
typedef __attribute__((ext_vector_type(8))) unsigned short ushort8;
typedef __attribute__((ext_vector_type(4))) float float4v;

#define DM    2048
#define INNERC 4096
#define LSEQ  4096
#define NBATCH 2
#define MROWS 8192      // NBATCH*LSEQ
#define NHH   64
#define HDD   64
#define NCHUNK 32
#define CHLEN  128
#define CROWS 8         // conv rows per block

__device__ __forceinline__ float bf2f(ushort u) {
    return __uint_as_float(((unsigned int)u) << 16);
}
__device__ __forceinline__ ushort f2bf(float f) {
    unsigned int u = __float_as_uint(f);
    unsigned int r = u + 0x7FFFu + ((u >> 16) & 1u);
    return (ushort)(r >> 16);
}

// async global->LDS 16B copy. LDS dest must be wave-uniform base + lane*16.
__device__ __forceinline__ void async_cp16(const ushort* __restrict__ g, ushort* l) {
    __builtin_amdgcn_global_load_lds(
        (const __attribute__((address_space(1))) unsigned int*)g,
        (__attribute__((address_space(3))) unsigned int*)l,
        16, 0, 0);
}

// ---------------- diagnostic ----------------
__global__ void diag_kernel(float* __restrict__ out, float val) {
    if (threadIdx.x == 0 && blockIdx.x == 0) out[0] = val;
}

// ---------------- f32 -> bf16 cast ----------------
__global__ __launch_bounds__(256) void cast_bf16_kernel(
    const float* __restrict__ in, ushort* __restrict__ out, int n) {
    const int i = (blockIdx.x * 256 + threadIdx.x) * 8;
    if (i + 8 > n) return;
    const float4v a = *(const float4v*)(in + i);
    const float4v b = *(const float4v*)(in + i + 4);
    ushort8 o;
    o[0] = f2bf(a[0]); o[1] = f2bf(a[1]); o[2] = f2bf(a[2]); o[3] = f2bf(a[3]);
    o[4] = f2bf(b[0]); o[5] = f2bf(b[1]); o[6] = f2bf(b[2]); o[7] = f2bf(b[3]);
    *(ushort8*)(out + i) = o;
}

// ---------------- bf16 bt-GEMM, 256x256 tile, 8-phase counted-vmcnt ----------
// Out(M,N) = A(M,K) * W(N,K)^T.  512 threads = 8 waves (2M x 4N); per-wave
// output 128x64 -> acc[8][4].  LDS 128 KiB (2 dbuf x (A 32K + B 32K)).
// Granule swizzle: 16B granule (row, q) stored at slot row*8 + (q ^ (row&7)).
//
// m201-faithful phase structure (reads distributed {12,4,8,0} per K-tile):
//   p1: read afL (A rows +0..63, 8x b128) + bf[0-1] (4x) ; lgkmcnt(8)
//       -> bar, lgkm0, MFMA Q(rm0-3,cn0-1), bar
//   p2: read bf[2-3] (4x)                 -> MFMA Q(rm0-3,cn2-3)
//   p3: read afH (A rows +64..127, 8x)    ; stage (u+2).Bh0
//                                         -> MFMA Q(rm4-7,cn2-3)
//   p4: stage (u+2).Bh1 -> MFMA Q(rm4-7,cn0-1) ; vmcnt(4) ; bar
//   p5-p8: same on buf1; stages: p5 (u+2).Ah0, p6 (u+2).Ah1,
//          p7 (u+3).Bh0+Bh1, p8 (u+3).Ah0+Ah1 ; vmcnt(8) at p8.
// Stage liveness (barrier-ordered): buf0.B last read at p2 -> staged p3/p4;
// buf0.A last read at p3 -> staged p5/p6; buf1.B last read p6 -> p7;
// buf1.A last read p7 -> p8.  Gates: at p4, 4 outstanding (p3+p4) => all of
// prev iter's p8 (tile u+1) landed before p5 reads buf1.  At p8, 8
// outstanding (p7+p8) => tile u+2 (staged p3-p6) landed before next p1.
// No sched_barrier(0) anywhere (m141).  EPI: 0 bf16, 1 sigmoid*Aux, 2 f32.

#define PH_PRE() do { \
    __builtin_amdgcn_s_barrier(); \
    asm volatile("s_waitcnt lgkmcnt(0)"); } while (0)

#define PH_POST() do { \
    __builtin_amdgcn_s_barrier(); } while (0)

#define MFMA_Q(AF, RBASE, CL) do { \
    __builtin_amdgcn_s_setprio(1); \
    _Pragma("unroll") for (int rm = 0; rm < 4; ++rm) \
    _Pragma("unroll") for (int cn = 0; cn < 2; ++cn) \
    _Pragma("unroll") for (int kk = 0; kk < 2; ++kk) \
        acc[(RBASE) + rm][(CL) + cn] = __builtin_amdgcn_mfma_f32_16x16x32_bf16( \
            AF[rm][kk], bf[(CL) + cn][kk], acc[(RBASE) + rm][(CL) + cn], 0, 0, 0); \
    __builtin_amdgcn_s_setprio(0); } while (0)

#define READ_A(DST, BUF, HB) do { \
    _Pragma("unroll") for (int rm = 0; rm < 4; ++rm) \
    _Pragma("unroll") for (int kk = 0; kk < 2; ++kk) { \
        const int rA = wm * 128 + (HB) * 64 + rm * 16 + l15; \
        DST[rm][kk] = *(const short8*)&As[BUF][ \
            (rA * 8 + ((kk * 4 + l4) ^ swz7)) * 8]; \
    } } while (0)

#define READ_B2(BUF, CNLO) do { \
    _Pragma("unroll") for (int cn = 0; cn < 2; ++cn) \
    _Pragma("unroll") for (int kk = 0; kk < 2; ++kk) { \
        const int rB = wn * 64 + ((CNLO) + cn) * 16 + l15; \
        bf[(CNLO) + cn][kk] = *(const short8*)&Bs[BUF][ \
            (rB * 8 + ((kk * 4 + l4) ^ swz7)) * 8]; \
    } } while (0)

template <int EPI>
__global__ __launch_bounds__(512, 2) void gemm256(
    const ushort* __restrict__ Ab, const ushort* __restrict__ Wb,
    void* __restrict__ Out, const ushort* __restrict__ Aux,
    int M, int N, int K) {
    __shared__ ushort As[2][16384];
    __shared__ ushort Bs[2][16384];

    const int tid  = threadIdx.x;
    const int lane = tid & 63;
    const int w    = tid >> 6;
    const int wm   = w >> 2;          // 0..1
    const int wn   = w & 3;           // 0..3
    const int l15  = lane & 15;
    const int l4   = lane >> 4;       // 0..3
    const int swz7 = l15 & 7;

    // XCD-aware block swizzle (nwg divisible by 8 for all our shapes)
    const int gx   = gridDim.x;
    const int nwg  = gx * gridDim.y;
    const int orig = blockIdx.y * gx + blockIdx.x;
    const int swz  = (orig & 7) * (nwg >> 3) + (orig >> 3);
    const int row0 = (swz / gx) * 256;
    const int col0 = (swz % gx) * 256;

    const int ni = K >> 7;            // iterations (2 K-tiles each)

    float4v acc[8][4];
#pragma unroll
    for (int i2 = 0; i2 < 8; i2++)
#pragma unroll
        for (int j2 = 0; j2 < 4; j2++) {
            float4v z = {0.f, 0.f, 0.f, 0.f};
            acc[i2][j2] = z;
        }

    short8 afL[4][2], afH[4][2], bf[4][2];

    // stage one half-tile (128 rows x 64 k), 2 loads/thread
    auto stage = [&](const ushort* __restrict__ G, int grow0, int t, ushort* dst) {
#pragma unroll
        for (int j = 0; j < 2; ++j) {
            const int c  = j * 512 + tid;
            const int r  = c >> 3;
            const int kg = (c & 7) ^ (r & 7);
            async_cp16(G + (size_t)(grow0 + r) * K + (t << 6) + kg * 8, dst + c * 8);
        }
    };

    // -------- prologue: tile0 (buf0) + tile1 (buf1), then wait tile0
    stage(Ab, row0,       0, &As[0][0]);
    stage(Ab, row0 + 128, 0, &As[0][8192]);
    stage(Wb, col0,       0, &Bs[0][0]);
    stage(Wb, col0 + 128, 0, &Bs[0][8192]);
    stage(Ab, row0,       1, &As[1][0]);
    stage(Ab, row0 + 128, 1, &As[1][8192]);
    stage(Wb, col0,       1, &Bs[1][0]);
    stage(Wb, col0 + 128, 1, &Bs[1][8192]);
    asm volatile("s_waitcnt vmcnt(8)" ::: "memory");   // tile0 landed
    __builtin_amdgcn_s_barrier();

#pragma unroll 1
    for (int i = 0; i < ni; ++i) {
        const int u = 2 * i;
        const bool last = (i == ni - 1);

        // ---- p1: buf0, Q(rm0-3, cn0-1); 12 ds_reads
        READ_A(afL, 0, 0);
        READ_B2(0, 0);
        asm volatile("s_waitcnt lgkmcnt(8)");
        PH_PRE();
        MFMA_Q(afL, 0, 0);
        PH_POST();

        // ---- p2: Q(rm0-3, cn2-3); 4 ds_reads
        READ_B2(0, 2);
        PH_PRE();
        MFMA_Q(afL, 0, 2);
        PH_POST();

        // ---- p3: Q(rm4-7, cn2-3); 8 ds_reads; stage (u+2).Bh0
        READ_A(afH, 0, 1);
        if (!last) stage(Wb, col0, u + 2, &Bs[0][0]);
        PH_PRE();
        MFMA_Q(afH, 4, 2);
        PH_POST();

        // ---- p4: Q(rm4-7, cn0-1); stage (u+2).Bh1; gate buf1 (tile u+1)
        if (!last) stage(Wb, col0 + 128, u + 2, &Bs[0][8192]);
        PH_PRE();
        MFMA_Q(afH, 4, 0);
        if (last) { asm volatile("s_waitcnt vmcnt(0)" ::: "memory"); }
        else      { asm volatile("s_waitcnt vmcnt(4)" ::: "memory"); }
        __builtin_amdgcn_s_barrier();

        // ---- p5: buf1, Q(rm0-3, cn0-1); stage (u+2).Ah0
        READ_A(afL, 1, 0);
        READ_B2(1, 0);
        if (!last) stage(Ab, row0, u + 2, &As[0][0]);
        asm volatile("s_waitcnt lgkmcnt(8)");
        PH_PRE();
        MFMA_Q(afL, 0, 0);
        PH_POST();

        // ---- p6: Q(rm0-3, cn2-3); stage (u+2).Ah1
        READ_B2(1, 2);
        if (!last) stage(Ab, row0 + 128, u + 2, &As[0][8192]);
        PH_PRE();
        MFMA_Q(afL, 0, 2);
        PH_POST();

        // ---- p7: Q(rm4-7, cn2-3); stage (u+3).Bh0+Bh1
        READ_A(afH, 1, 1);
        if (!last) {
            stage(Wb, col0,       u + 3, &Bs[1][0]);
            stage(Wb, col0 + 128, u + 3, &Bs[1][8192]);
        }
        PH_PRE();
        MFMA_Q(afH, 4, 2);
        PH_POST();

        // ---- p8: Q(rm4-7, cn0-1); stage (u+3).Ah0+Ah1; gate buf0 (tile u+2)
        if (!last) {
            stage(Ab, row0,       u + 3, &As[1][0]);
            stage(Ab, row0 + 128, u + 3, &As[1][8192]);
        }
        PH_PRE();
        MFMA_Q(afH, 4, 0);
        if (!last) { asm volatile("s_waitcnt vmcnt(8)" ::: "memory"); }
        __builtin_amdgcn_s_barrier();
    }

    // epilogue: C/D layout col = lane&15, row = (lane>>4)*4 + reg
#pragma unroll
    for (int rm = 0; rm < 8; ++rm) {
#pragma unroll
        for (int cn = 0; cn < 4; ++cn) {
            const int r0 = row0 + wm * 128 + rm * 16 + l4 * 4;
            const int cc = col0 + wn * 64 + cn * 16 + l15;
#pragma unroll
            for (int rr = 0; rr < 4; ++rr) {
                const float v = acc[rm][cn][rr];
                const size_t off = (size_t)(r0 + rr) * N + cc;
                if (EPI == 0) {
                    ((ushort*)Out)[off] = f2bf(v);
                } else if (EPI == 1) {
                    const float g = 1.0f / (1.0f + __expf(-v));
                    ((ushort*)Out)[off] = f2bf(g * bf2f(Aux[off]));
                } else {
                    ((float*)Out)[off] = v;
                }
            }
        }
    }
}

// ---------------- depthwise causal conv (K=4) + SiLU ----------------
__global__ __launch_bounds__(256) void conv_silu_kernel(
    const ushort* __restrict__ proj, const float* __restrict__ cw,
    const float* __restrict__ cb, ushort* __restrict__ X) {
    const int blk  = blockIdx.x;          // 2048 blocks
    const int half = blk & 1;
    const int tile = blk >> 1;            // 1024 tiles of 8 rows
    const int bl0  = tile * CROWS;
    const bool atStart = ((bl0 & (LSEQ - 1)) == 0);
    const int c0 = half * 2048 + threadIdx.x * 8;

    float4v w[8];
    const float4v* wp4 = (const float4v*)(cw + (size_t)c0 * 4);
#pragma unroll
    for (int t = 0; t < 8; t++) w[t] = wp4[t];
    float bias[8];
    const float4v b0 = *(const float4v*)(cb + c0);
    const float4v b1 = *(const float4v*)(cb + c0 + 4);
#pragma unroll
    for (int t = 0; t < 4; t++) { bias[t] = b0[t]; bias[t + 4] = b1[t]; }

    const size_t base = (size_t)bl0 * INNERC + c0;
    ushort8 w0, w1, w2;
    const ushort8 zz = {0, 0, 0, 0, 0, 0, 0, 0};
    if (atStart) {
        w0 = zz; w1 = zz; w2 = zz;
    } else {
        w0 = *(const ushort8*)(proj + base - 3 * (size_t)INNERC);
        w1 = *(const ushort8*)(proj + base - 2 * (size_t)INNERC);
        w2 = *(const ushort8*)(proj + base - 1 * (size_t)INNERC);
    }
#pragma unroll
    for (int r = 0; r < CROWS; r++) {
        const ushort8 cur = *(const ushort8*)(proj + base + (size_t)r * INNERC);
        ushort8 o;
#pragma unroll
        for (int j = 0; j < 8; j++) {
            const float acc = bias[j]
                + w[j][0] * bf2f(w0[j]) + w[j][1] * bf2f(w1[j])
                + w[j][2] * bf2f(w2[j]) + w[j][3] * bf2f(cur[j]);
            o[j] = f2bf(acc / (1.0f + __expf(-acc)));   // silu
        }
        *(ushort8*)(X + base + (size_t)r * INNERC) = o;
        w0 = w1; w1 = w2; w2 = cur;
    }
}

// ---------------- dt = softplus(sum_p X*dt_w + dt_b) ----------------
__global__ __launch_bounds__(64) void dt_kernel(
    const ushort* __restrict__ X, const float* __restrict__ dtw,
    const float* __restrict__ dtb, float* __restrict__ dt) {
    const int bl = blockIdx.x;
    const int h  = threadIdx.x;
    const ushort* xp = X + (size_t)bl * INNERC + h * 64;
    const float*  wp = dtw + h * 64;
    float acc = 0.0f;
#pragma unroll
    for (int p0 = 0; p0 < 64; p0 += 8) {
        const ushort8 xv = *(const ushort8*)(xp + p0);
#pragma unroll
        for (int j = 0; j < 8; j++) acc += bf2f(xv[j]) * wp[p0 + j];
    }
    const float z = acc + dtb[h];
    dt[bl * 64 + h] = (z > 20.0f) ? z : __logf(1.0f + __expf(z));
}

// ---------------- chunked diagonal scan ----------------
__global__ __launch_bounds__(256) void scan_pass1(
    const ushort* __restrict__ X, const float* __restrict__ dt,
    const float* __restrict__ A_log, const float* __restrict__ Bv,
    float* __restrict__ sumP, float* __restrict__ sumS) {
    const int task = blockIdx.x * 4 + (threadIdx.x >> 6);
    const int p  = threadIdx.x & 63;
    const int ch = task & (NCHUNK - 1);
    const int bh = task >> 5;
    const int h  = bh & 63;
    const int b  = bh >> 6;
    const float Ac = -__expf(A_log[h * 64 + p]);
    const float Bc = Bv[h * 64 + p];
    float Pr = 1.0f, s = 0.0f;
    const int bl0 = b * LSEQ + ch * CHLEN;
#pragma unroll 4
    for (int i = 0; i < CHLEN; i++) {
        const int bl   = bl0 + i;
        const float dtv = dt[bl * 64 + h];
        const float x   = bf2f(X[(size_t)bl * INNERC + h * 64 + p]);
        const float a   = __expf(dtv * Ac);
        Pr *= a;
        s = a * s + dtv * Bc * x;
    }
    sumP[(size_t)task * 64 + p] = Pr;
    sumS[(size_t)task * 64 + p] = s;
}

__global__ __launch_bounds__(64) void scan_pass2(
    const float* __restrict__ sumP, const float* __restrict__ sumS,
    float* __restrict__ carry) {
    const int bh = blockIdx.x;
    const int p  = threadIdx.x;
    float c = 0.0f;
    for (int ch = 0; ch < NCHUNK; ch++) {
        const size_t idx = ((size_t)bh * NCHUNK + ch) * 64 + p;
        carry[idx] = c;
        c = sumP[idx] * c + sumS[idx];
    }
}

__global__ __launch_bounds__(256) void scan_pass3(
    const ushort* __restrict__ X, const float* __restrict__ dt,
    const float* __restrict__ carry,
    const float* __restrict__ A_log, const float* __restrict__ Bv,
    const float* __restrict__ Cv, const float* __restrict__ Dv,
    ushort* __restrict__ Y) {
    const int task = blockIdx.x * 4 + (threadIdx.x >> 6);
    const int p  = threadIdx.x & 63;
    const int ch = task & (NCHUNK - 1);
    const int bh = task >> 5;
    const int h  = bh & 63;
    const int b  = bh >> 6;
    const float Ac = -__expf(A_log[h * 64 + p]);
    const float Bc = Bv[h * 64 + p];
    const float Cc = Cv[h * 64 + p];
    const float Dc = Dv[h * 64 + p];
    float s = carry[(size_t)task * 64 + p];
    const int bl0 = b * LSEQ + ch * CHLEN;
#pragma unroll 2
    for (int i = 0; i < CHLEN; i++) {
        const int bl = bl0 + i;
        const size_t xoff = (size_t)bl * INNERC + h * 64 + p;
        const float dtv = dt[bl * 64 + h];
        const float x   = bf2f(X[xoff]);
        const float a   = __expf(dtv * Ac);
        s = a * s + dtv * Bc * x;
        Y[xoff] = f2bf(Cc * s + Dc * x);
    }
}

// ---------------- workspace layout (bytes) ----------------
#define OFF_PROJ  ((size_t)0)            // 67,108,864 : proj -> Y -> comb
#define OFF_HID   ((size_t)67108864)     // 33,554,432 : hidden bf16
#define OFF_WB    ((size_t)100663296)    // 16,777,216 : weight bf16 (reused 3x)
#define OFF_DT    ((size_t)117440512)    //  2,097,152
#define OFF_SUMP  ((size_t)119537664)    //  1,048,576
#define OFF_SUMS  ((size_t)120586240)    //  1,048,576
#define OFF_CARRY ((size_t)121634816)    //  1,048,576
#define WS_NEEDED ((size_t)122683392)    // = 117 MiB

extern "C" void kernel_launch(void* const* d_in, const int* in_sizes, int n_in,
                              void* d_out, int out_size, void* d_ws, size_t ws_size,
                              hipStream_t stream) {
    if (ws_size < WS_NEEDED) {
        diag_kernel<<<1, 64, 0, stream>>>((float*)d_out, (float)(ws_size >> 20));
        return;
    }
    const float* hidden = (const float*)d_in[0];
    const float* w_in   = (const float*)d_in[1];
    const float* w_gate = (const float*)d_in[2];
    const float* w_out  = (const float*)d_in[3];
    const float* conv_w = (const float*)d_in[4];
    const float* conv_b = (const float*)d_in[5];
    const float* dt_w   = (const float*)d_in[6];
    const float* dt_b   = (const float*)d_in[7];
    const float* A_log  = (const float*)d_in[8];
    const float* Bv     = (const float*)d_in[9];
    const float* Cv     = (const float*)d_in[10];
    const float* Dv     = (const float*)d_in[11];

    char* ws = (char*)d_ws;
    ushort* projbuf = (ushort*)(ws + OFF_PROJ);   // proj, then Y, then comb
    ushort* hid16   = (ushort*)(ws + OFF_HID);
    ushort* wbuf    = (ushort*)(ws + OFF_WB);
    float*  dtf     = (float*)(ws + OFF_DT);
    float*  sumP    = (float*)(ws + OFF_SUMP);
    float*  sumS    = (float*)(ws + OFF_SUMS);
    float*  carry   = (float*)(ws + OFF_CARRY);
    ushort* x16     = (ushort*)d_out;             // X scratch inside d_out

    // hidden + in_proj weight casts
    cast_bf16_kernel<<<8192, 256, 0, stream>>>(hidden, hid16, MROWS * DM);
    cast_bf16_kernel<<<4096, 256, 0, stream>>>(w_in, wbuf, INNERC * DM);

    // in_proj GEMM -> proj (bf16)
    gemm256<0><<<dim3(INNERC / 256, MROWS / 256), 512, 0, stream>>>(
        hid16, wbuf, projbuf, nullptr, MROWS, INNERC, DM);

    // conv + silu -> X (in d_out), then dt
    conv_silu_kernel<<<(MROWS / CROWS) * 2, 256, 0, stream>>>(projbuf, conv_w, conv_b, x16);
    dt_kernel<<<MROWS, 64, 0, stream>>>(x16, dt_w, dt_b, dtf);

    // chunked scan; pass3 writes y into projbuf (proj dead after conv)
    scan_pass1<<<(NBATCH * NHH * NCHUNK) / 4, 256, 0, stream>>>(
        x16, dtf, A_log, Bv, sumP, sumS);
    scan_pass2<<<NBATCH * NHH, 64, 0, stream>>>(sumP, sumS, carry);
    scan_pass3<<<(NBATCH * NHH * NCHUNK) / 4, 256, 0, stream>>>(
        x16, dtf, carry, A_log, Bv, Cv, Dv, projbuf);

    // gate GEMM with fused gating: comb = sigmoid(G) * Y, in-place in projbuf
    cast_bf16_kernel<<<4096, 256, 0, stream>>>(w_gate, wbuf, INNERC * DM);
    gemm256<1><<<dim3(INNERC / 256, MROWS / 256), 512, 0, stream>>>(
        hid16, wbuf, projbuf, projbuf, MROWS, INNERC, DM);

    // output projection (f32 out) — overwrites X scratch in d_out
    cast_bf16_kernel<<<4096, 256, 0, stream>>>(w_out, wbuf, DM * INNERC);
    gemm256<2><<<dim3(DM / 256, MROWS / 256), 512, 0, stream>>>(
        projbuf, wbuf, d_out, nullptr, MROWS, DM, INNERC);
}

// Round 4
// 647.549 us; speedup vs baseline: 1.2025x; 1.0553x over previous
//
#include <hip/hip_runtime.h>
#include <cstdint>
#include <cstddef>

typedef unsigned short ushort;
typedef unsigned int uint;
typedef __attribute__((ext_vector_type(8))) short short8;
typedef __attribute__((ext_vector_type(8))) unsigned short ushort8;
typedef __attribute__((ext_vector_type(4))) float float4v;

#define DM    2048
#define INNERC 4096
#define LSEQ  4096
#define NBATCH 2
#define MROWS 8192      // NBATCH*LSEQ
#define NHH   64
#define HDD   64
#define NCHUNK 32
#define CHLEN  128
#define CROWS 8         // conv rows per block

__device__ __forceinline__ float bf2f(ushort u) {
    return __uint_as_float(((unsigned int)u) << 16);
}
__device__ __forceinline__ ushort f2bf(float f) {
    unsigned int u = __float_as_uint(f);
    unsigned int r = u + 0x7FFFu + ((u >> 16) & 1u);
    return (ushort)(r >> 16);
}

// async global->LDS 16B copy. LDS dest must be wave-uniform base + lane*16.
__device__ __forceinline__ void async_cp16(const ushort* __restrict__ g, ushort* l) {
    __builtin_amdgcn_global_load_lds(
        (const __attribute__((address_space(1))) unsigned int*)g,
        (__attribute__((address_space(3))) unsigned int*)l,
        16, 0, 0);
}

// ---------------- diagnostic ----------------
__global__ void diag_kernel(float* __restrict__ out, float val) {
    if (threadIdx.x == 0 && blockIdx.x == 0) out[0] = val;
}

// ---------------- f32 -> bf16 cast ----------------
__global__ __launch_bounds__(256) void cast_bf16_kernel(
    const float* __restrict__ in, ushort* __restrict__ out, int n) {
    const int i = (blockIdx.x * 256 + threadIdx.x) * 8;
    if (i + 8 > n) return;
    const float4v a = *(const float4v*)(in + i);
    const float4v b = *(const float4v*)(in + i + 4);
    ushort8 o;
    o[0] = f2bf(a[0]); o[1] = f2bf(a[1]); o[2] = f2bf(a[2]); o[3] = f2bf(a[3]);
    o[4] = f2bf(b[0]); o[5] = f2bf(b[1]); o[6] = f2bf(b[2]); o[7] = f2bf(b[3]);
    *(ushort8*)(out + i) = o;
}

// ---------------- bf16 bt-GEMM, 256x256 tile, 8-phase counted-vmcnt ----------
// Out(M,N) = A(M,K) * W(N,K)^T.  512 threads = 8 waves (2M x 4N); per-wave
// output 128x64 -> acc[8][4].  LDS 128 KiB (2 dbuf x (A 32K + B 32K)).
// Granule swizzle: 16B granule (row, q) at slot row*8 + (q ^ (row&7)).
// All ds_read addresses are base-register + compile-time immediate (XOR
// decomposed); staging uses 4 per-thread 32-bit offsets advanced by +64
// elems per use; last iteration peeled (branch-free main loop).
// Phase/gate structure identical to round 2 (proven correct):
// reads {12,4,8,0} per K-tile, stages p3..p8, vmcnt(4)@p4 / vmcnt(8)@p8.
// EPI: 0 bf16, 1 sigmoid(acc)*Aux -> bf16 (in-place ok), 2 f32.

#define PH_PRE() do { \
    __builtin_amdgcn_s_barrier(); \
    asm volatile("s_waitcnt lgkmcnt(0)"); } while (0)

#define PH_POST() do { \
    __builtin_amdgcn_s_barrier(); } while (0)

#define MFMA_Q(AF, RBASE, CL) do { \
    __builtin_amdgcn_s_setprio(1); \
    _Pragma("unroll") for (int kk = 0; kk < 2; ++kk) \
    _Pragma("unroll") for (int rm = 0; rm < 4; ++rm) \
    _Pragma("unroll") for (int cn = 0; cn < 2; ++cn) \
        acc[(RBASE) + rm][(CL) + cn] = __builtin_amdgcn_mfma_f32_16x16x32_bf16( \
            AF[rm][kk], bf[(CL) + cn][kk], acc[(RBASE) + rm][(CL) + cn], 0, 0, 0); \
    __builtin_amdgcn_s_setprio(0); } while (0)

// A-read: elem = rA*64 + (kq^swz7)*8 ; rA = wm*128 + HB*64 + rm*16 + l15.
// Decomposed: offA_k{0,1} holds (wm*128+l15)*64 + (l4^s01)*8 + ((kk^b2))*32;
// the (HB*4+rm)*1024-elem part is a compile-time ds_read offset immediate.
#define READ_A(DST, BUF, HB) do { \
    _Pragma("unroll") for (int rm = 0; rm < 4; ++rm) { \
        DST[rm][0] = *(const short8*)&As[BUF][offA_k0 + ((HB) * 4 + rm) * 1024]; \
        DST[rm][1] = *(const short8*)&As[BUF][offA_k1 + ((HB) * 4 + rm) * 1024]; \
    } } while (0)

#define READ_B2(BUF, CNLO) do { \
    _Pragma("unroll") for (int cn = 0; cn < 2; ++cn) { \
        bf[(CNLO) + cn][0] = *(const short8*)&Bs[BUF][offB_k0 + ((CNLO) + cn) * 1024]; \
        bf[(CNLO) + cn][1] = *(const short8*)&Bs[BUF][offB_k1 + ((CNLO) + cn) * 1024]; \
    } } while (0)

// stage one half-tile (128 rows x 64 k): 2 loads/thread, then advance the
// per-thread source offset to the next K-tile (+64 elems).
#define STAGE(G, OFF, LBASE) do { \
    async_cp16((G) + (OFF),       (LBASE) + (tid << 3)); \
    async_cp16((G) + (OFF) + k64, (LBASE) + (tid << 3) + 4096); \
    (OFF) += 64; } while (0)

template <int EPI>
__global__ __launch_bounds__(512, 2) void gemm256(
    const ushort* __restrict__ Ab, const ushort* __restrict__ Wb,
    void* __restrict__ Out, const ushort* __restrict__ Aux,
    int M, int N, int K) {
    __shared__ ushort As[2][16384];
    __shared__ ushort Bs[2][16384];

    const int tid  = threadIdx.x;
    const int lane = tid & 63;
    const int w    = tid >> 6;
    const int wm   = w >> 2;          // 0..1
    const int wn   = w & 3;           // 0..3
    const int l15  = lane & 15;
    const int l4   = lane >> 4;       // 0..3
    const int swz7 = l15 & 7;
    const int s01  = swz7 & 3;
    const int b2   = (swz7 >> 2) & 1;

    // XCD-aware block swizzle (nwg divisible by 8 for all our shapes)
    const int gx   = gridDim.x;
    const int nwg  = gx * gridDim.y;
    const int orig = blockIdx.y * gx + blockIdx.x;
    const int swz  = (orig & 7) * (nwg >> 3) + (orig >> 3);
    const int row0 = (swz / gx) * 256;
    const int col0 = (swz % gx) * 256;

    const int ni = K >> 7;            // iterations (2 K-tiles each)

    // precomputed LDS read base offsets (elem units)
    const int commA   = (wm * 128 + l15) * 64 + (l4 ^ s01) * 8;
    const int offA_k0 = commA + (b2 ? 32 : 0);
    const int offA_k1 = commA + (b2 ? 0 : 32);
    const int commB   = (wn * 64 + l15) * 64 + (l4 ^ s01) * 8;
    const int offB_k0 = commB + (b2 ? 32 : 0);
    const int offB_k1 = commB + (b2 ? 0 : 32);

    // precomputed per-thread staging source offsets (elem units)
    const uint rr8 = (uint)(tid >> 3);
    const uint kg8 = (uint)(((tid & 7) ^ ((tid >> 3) & 7)) * 8);
    const uint k64 = (uint)64 * (uint)K;            // 64-row stride (j=1)
    uint oA0 = (uint)(row0) * (uint)K + rr8 * (uint)K + kg8;
    uint oA1 = oA0 + (uint)128 * (uint)K;
    uint oW0 = (uint)(col0) * (uint)K + rr8 * (uint)K + kg8;
    uint oW1 = oW0 + (uint)128 * (uint)K;

    float4v acc[8][4];
#pragma unroll
    for (int i2 = 0; i2 < 8; i2++)
#pragma unroll
        for (int j2 = 0; j2 < 4; j2++) {
            float4v z = {0.f, 0.f, 0.f, 0.f};
            acc[i2][j2] = z;
        }

    short8 afL[4][2], afH[4][2], bf[4][2];

    // -------- prologue: tiles 0 (buf0) and 1 (buf1); wait tile0
    STAGE(Ab, oA0, &As[0][0]);
    STAGE(Ab, oA1, &As[0][8192]);
    STAGE(Wb, oW0, &Bs[0][0]);
    STAGE(Wb, oW1, &Bs[0][8192]);
    STAGE(Ab, oA0, &As[1][0]);
    STAGE(Ab, oA1, &As[1][8192]);
    STAGE(Wb, oW0, &Bs[1][0]);
    STAGE(Wb, oW1, &Bs[1][8192]);
    asm volatile("s_waitcnt vmcnt(8)" ::: "memory");   // tile0 landed
    __builtin_amdgcn_s_barrier();

#pragma unroll 1
    for (int i = 0; i < ni - 1; ++i) {
        // ---- p1: buf0, Q(rm0-3, cn0-1); 12 ds_reads
        READ_A(afL, 0, 0);
        READ_B2(0, 0);
        asm volatile("s_waitcnt lgkmcnt(8)");
        PH_PRE();
        MFMA_Q(afL, 0, 0);
        PH_POST();

        // ---- p2: Q(rm0-3, cn2-3)
        READ_B2(0, 2);
        PH_PRE();
        MFMA_Q(afL, 0, 2);
        PH_POST();

        // ---- p3: Q(rm4-7, cn2-3); stage (u+2).Bh0
        READ_A(afH, 0, 1);
        STAGE(Wb, oW0, &Bs[0][0]);
        PH_PRE();
        MFMA_Q(afH, 4, 2);
        PH_POST();

        // ---- p4: Q(rm4-7, cn0-1); stage (u+2).Bh1; gate buf1 (tile u+1)
        STAGE(Wb, oW1, &Bs[0][8192]);
        PH_PRE();
        MFMA_Q(afH, 4, 0);
        asm volatile("s_waitcnt vmcnt(4)" ::: "memory");
        __builtin_amdgcn_s_barrier();

        // ---- p5: buf1, Q(rm0-3, cn0-1); stage (u+2).Ah0
        READ_A(afL, 1, 0);
        READ_B2(1, 0);
        STAGE(Ab, oA0, &As[0][0]);
        asm volatile("s_waitcnt lgkmcnt(8)");
        PH_PRE();
        MFMA_Q(afL, 0, 0);
        PH_POST();

        // ---- p6: Q(rm0-3, cn2-3); stage (u+2).Ah1
        READ_B2(1, 2);
        STAGE(Ab, oA1, &As[0][8192]);
        PH_PRE();
        MFMA_Q(afL, 0, 2);
        PH_POST();

        // ---- p7: Q(rm4-7, cn2-3); stage (u+3).Bh0+Bh1
        READ_A(afH, 1, 1);
        STAGE(Wb, oW0, &Bs[1][0]);
        STAGE(Wb, oW1, &Bs[1][8192]);
        PH_PRE();
        MFMA_Q(afH, 4, 2);
        PH_POST();

        // ---- p8: Q(rm4-7, cn0-1); stage (u+3).Ah0+Ah1; gate buf0 (tile u+2)
        STAGE(Ab, oA0, &As[1][0]);
        STAGE(Ab, oA1, &As[1][8192]);
        PH_PRE();
        MFMA_Q(afH, 4, 0);
        asm volatile("s_waitcnt vmcnt(8)" ::: "memory");
        __builtin_amdgcn_s_barrier();
    }

    // -------- peeled last iteration: no stages, no intra-phase barriers
    {
        // buf0 (tile 2ni-2): landed (prev p8 gate vmcnt(8) drained p3-p6)
        READ_A(afL, 0, 0);
        READ_B2(0, 0);
        READ_B2(0, 2);
        READ_A(afH, 0, 1);
        __builtin_amdgcn_s_setprio(1);
        MFMA_Q(afL, 0, 0);
        MFMA_Q(afL, 0, 2);
        MFMA_Q(afH, 4, 2);
        MFMA_Q(afH, 4, 0);
        __builtin_amdgcn_s_setprio(0);
        // buf1 (tile 2ni-1): wait own DMA then all waves' DMA
        asm volatile("s_waitcnt vmcnt(0)" ::: "memory");
        __builtin_amdgcn_s_barrier();
        READ_A(afL, 1, 0);
        READ_B2(1, 0);
        READ_B2(1, 2);
        READ_A(afH, 1, 1);
        __builtin_amdgcn_s_setprio(1);
        MFMA_Q(afL, 0, 0);
        MFMA_Q(afL, 0, 2);
        MFMA_Q(afH, 4, 2);
        MFMA_Q(afH, 4, 0);
        __builtin_amdgcn_s_setprio(0);
    }

    // epilogue: C/D layout col = lane&15, row = (lane>>4)*4 + reg
#pragma unroll
    for (int rm = 0; rm < 8; ++rm) {
#pragma unroll
        for (int cn = 0; cn < 4; ++cn) {
            const int r0 = row0 + wm * 128 + rm * 16 + l4 * 4;
            const int cc = col0 + wn * 64 + cn * 16 + l15;
#pragma unroll
            for (int rr = 0; rr < 4; ++rr) {
                const float v = acc[rm][cn][rr];
                const size_t off = (size_t)(r0 + rr) * N + cc;
                if (EPI == 0) {
                    ((ushort*)Out)[off] = f2bf(v);
                } else if (EPI == 1) {
                    const float g = 1.0f / (1.0f + __expf(-v));
                    ((ushort*)Out)[off] = f2bf(g * bf2f(Aux[off]));
                } else {
                    ((float*)Out)[off] = v;
                }
            }
        }
    }
}

// ---------------- depthwise causal conv (K=4) + SiLU + fused dt ------------
// Each block: 8 consecutive rows x 2048 channels (one half).  Channels of a
// head are 8 consecutive threads (aligned within a wave), so dt's per-head
// reduction is 3 shfl_xor steps; lane leader writes softplus result.
__global__ __launch_bounds__(256) void conv_silu_kernel(
    const ushort* __restrict__ proj, const float* __restrict__ cw,
    const float* __restrict__ cb, const float* __restrict__ dtw,
    const float* __restrict__ dtb, ushort* __restrict__ X,
    float* __restrict__ dt) {
    const int blk  = blockIdx.x;          // 2048 blocks
    const int half = blk & 1;
    const int tile = blk >> 1;            // 1024 tiles of 8 rows
    const int bl0  = tile * CROWS;
    const bool atStart = ((bl0 & (LSEQ - 1)) == 0);
    const int c0 = half * 2048 + threadIdx.x * 8;
    const int h  = c0 >> 6;               // head of this thread's 8 channels

    float4v w[8];
    const float4v* wp4 = (const float4v*)(cw + (size_t)c0 * 4);
#pragma unroll
    for (int t = 0; t < 8; t++) w[t] = wp4[t];
    float bias[8];
    const float4v b0 = *(const float4v*)(cb + c0);
    const float4v b1 = *(const float4v*)(cb + c0 + 4);
#pragma unroll
    for (int t = 0; t < 4; t++) { bias[t] = b0[t]; bias[t + 4] = b1[t]; }

    float dtwv[8];
    const float4v d0 = *(const float4v*)(dtw + c0);
    const float4v d1 = *(const float4v*)(dtw + c0 + 4);
#pragma unroll
    for (int t = 0; t < 4; t++) { dtwv[t] = d0[t]; dtwv[t + 4] = d1[t]; }
    const float dtbv = dtb[h];

    const size_t base = (size_t)bl0 * INNERC + c0;
    ushort8 w0, w1, w2;
    const ushort8 zz = {0, 0, 0, 0, 0, 0, 0, 0};
    if (atStart) {
        w0 = zz; w1 = zz; w2 = zz;
    } else {
        w0 = *(const ushort8*)(proj + base - 3 * (size_t)INNERC);
        w1 = *(const ushort8*)(proj + base - 2 * (size_t)INNERC);
        w2 = *(const ushort8*)(proj + base - 1 * (size_t)INNERC);
    }
#pragma unroll
    for (int r = 0; r < CROWS; r++) {
        const ushort8 cur = *(const ushort8*)(proj + base + (size_t)r * INNERC);
        ushort8 o;
        float dacc = 0.0f;
#pragma unroll
        for (int j = 0; j < 8; j++) {
            const float acc = bias[j]
                + w[j][0] * bf2f(w0[j]) + w[j][1] * bf2f(w1[j])
                + w[j][2] * bf2f(w2[j]) + w[j][3] * bf2f(cur[j]);
            const float s = acc / (1.0f + __expf(-acc));   // silu
            o[j] = f2bf(s);
            dacc += s * dtwv[j];
        }
        *(ushort8*)(X + base + (size_t)r * INNERC) = o;
        // 8-lane reduce within the head group
        dacc += __shfl_xor(dacc, 1, 64);
        dacc += __shfl_xor(dacc, 2, 64);
        dacc += __shfl_xor(dacc, 4, 64);
        if ((threadIdx.x & 7) == 0) {
            const float z = dacc + dtbv;
            dt[(bl0 + r) * 64 + h] = (z > 20.0f) ? z : __logf(1.0f + __expf(z));
        }
        w0 = w1; w1 = w2; w2 = cur;
    }
}

// ---------------- chunked diagonal scan ----------------
__global__ __launch_bounds__(256) void scan_pass1(
    const ushort* __restrict__ X, const float* __restrict__ dt,
    const float* __restrict__ A_log, const float* __restrict__ Bv,
    float* __restrict__ sumP, float* __restrict__ sumS) {
    const int task = blockIdx.x * 4 + (threadIdx.x >> 6);
    const int p  = threadIdx.x & 63;
    const int ch = task & (NCHUNK - 1);
    const int bh = task >> 5;
    const int h  = bh & 63;
    const int b  = bh >> 6;
    const float Ac = -__expf(A_log[h * 64 + p]);
    const float Bc = Bv[h * 64 + p];
    float Pr = 1.0f, s = 0.0f;
    const int bl0 = b * LSEQ + ch * CHLEN;
#pragma unroll 4
    for (int i = 0; i < CHLEN; i++) {
        const int bl   = bl0 + i;
        const float dtv = dt[bl * 64 + h];
        const float x   = bf2f(X[(size_t)bl * INNERC + h * 64 + p]);
        const float a   = __expf(dtv * Ac);
        Pr *= a;
        s = a * s + dtv * Bc * x;
    }
    sumP[(size_t)task * 64 + p] = Pr;
    sumS[(size_t)task * 64 + p] = s;
}

__global__ __launch_bounds__(64) void scan_pass2(
    const float* __restrict__ sumP, const float* __restrict__ sumS,
    float* __restrict__ carry) {
    const int bh = blockIdx.x;
    const int p  = threadIdx.x;
    float c = 0.0f;
    for (int ch = 0; ch < NCHUNK; ch++) {
        const size_t idx = ((size_t)bh * NCHUNK + ch) * 64 + p;
        carry[idx] = c;
        c = sumP[idx] * c + sumS[idx];
    }
}

__global__ __launch_bounds__(256) void scan_pass3(
    const ushort* __restrict__ X, const float* __restrict__ dt,
    const float* __restrict__ carry,
    const float* __restrict__ A_log, const float* __restrict__ Bv,
    const float* __restrict__ Cv, const float* __restrict__ Dv,
    ushort* __restrict__ Y) {
    const int task = blockIdx.x * 4 + (threadIdx.x >> 6);
    const int p  = threadIdx.x & 63;
    const int ch = task & (NCHUNK - 1);
    const int bh = task >> 5;
    const int h  = bh & 63;
    const int b  = bh >> 6;
    const float Ac = -__expf(A_log[h * 64 + p]);
    const float Bc = Bv[h * 64 + p];
    const float Cc = Cv[h * 64 + p];
    const float Dc = Dv[h * 64 + p];
    float s = carry[(size_t)task * 64 + p];
    const int bl0 = b * LSEQ + ch * CHLEN;
#pragma unroll 2
    for (int i = 0; i < CHLEN; i++) {
        const int bl = bl0 + i;
        const size_t xoff = (size_t)bl * INNERC + h * 64 + p;
        const float dtv = dt[bl * 64 + h];
        const float x   = bf2f(X[xoff]);
        const float a   = __expf(dtv * Ac);
        s = a * s + dtv * Bc * x;
        Y[xoff] = f2bf(Cc * s + Dc * x);
    }
}

// ---------------- workspace layout (bytes) ----------------
#define OFF_PROJ  ((size_t)0)            // 67,108,864 : proj -> Y -> comb
#define OFF_HID   ((size_t)67108864)     // 33,554,432 : hidden bf16
#define OFF_WB    ((size_t)100663296)    // 16,777,216 : weight bf16 (reused 3x)
#define OFF_DT    ((size_t)117440512)    //  2,097,152
#define OFF_SUMP  ((size_t)119537664)    //  1,048,576
#define OFF_SUMS  ((size_t)120586240)    //  1,048,576
#define OFF_CARRY ((size_t)121634816)    //  1,048,576
#define WS_NEEDED ((size_t)122683392)    // = 117 MiB

extern "C" void kernel_launch(void* const* d_in, const int* in_sizes, int n_in,
                              void* d_out, int out_size, void* d_ws, size_t ws_size,
                              hipStream_t stream) {
    if (ws_size < WS_NEEDED) {
        diag_kernel<<<1, 64, 0, stream>>>((float*)d_out, (float)(ws_size >> 20));
        return;
    }
    const float* hidden = (const float*)d_in[0];
    const float* w_in   = (const float*)d_in[1];
    const float* w_gate = (const float*)d_in[2];
    const float* w_out  = (const float*)d_in[3];
    const float* conv_w = (const float*)d_in[4];
    const float* conv_b = (const float*)d_in[5];
    const float* dt_w   = (const float*)d_in[6];
    const float* dt_b   = (const float*)d_in[7];
    const float* A_log  = (const float*)d_in[8];
    const float* Bv     = (const float*)d_in[9];
    const float* Cv     = (const float*)d_in[10];
    const float* Dv     = (const float*)d_in[11];

    char* ws = (char*)d_ws;
    ushort* projbuf = (ushort*)(ws + OFF_PROJ);   // proj, then Y, then comb
    ushort* hid16   = (ushort*)(ws + OFF_HID);
    ushort* wbuf    = (ushort*)(ws + OFF_WB);
    float*  dtf     = (float*)(ws + OFF_DT);
    float*  sumP    = (float*)(ws + OFF_SUMP);
    float*  sumS    = (float*)(ws + OFF_SUMS);
    float*  carry   = (float*)(ws + OFF_CARRY);
    ushort* x16     = (ushort*)d_out;             // X scratch inside d_out

    // hidden + in_proj weight casts
    cast_bf16_kernel<<<8192, 256, 0, stream>>>(hidden, hid16, MROWS * DM);
    cast_bf16_kernel<<<4096, 256, 0, stream>>>(w_in, wbuf, INNERC * DM);

    // in_proj GEMM -> proj (bf16)
    gemm256<0><<<dim3(INNERC / 256, MROWS / 256), 512, 0, stream>>>(
        hid16, wbuf, projbuf, nullptr, MROWS, INNERC, DM);

    // conv + silu -> X (in d_out) with fused dt
    conv_silu_kernel<<<(MROWS / CROWS) * 2, 256, 0, stream>>>(
        projbuf, conv_w, conv_b, dt_w, dt_b, x16, dtf);

    // chunked scan; pass3 writes y into projbuf (proj dead after conv)
    scan_pass1<<<(NBATCH * NHH * NCHUNK) / 4, 256, 0, stream>>>(
        x16, dtf, A_log, Bv, sumP, sumS);
    scan_pass2<<<NBATCH * NHH, 64, 0, stream>>>(sumP, sumS, carry);
    scan_pass3<<<(NBATCH * NHH * NCHUNK) / 4, 256, 0, stream>>>(
        x16, dtf, carry, A_log, Bv, Cv, Dv, projbuf);

    // gate GEMM with fused gating: comb = sigmoid(G) * Y, in-place in projbuf
    cast_bf16_kernel<<<4096, 256, 0, stream>>>(w_gate, wbuf, INNERC * DM);
    gemm256<1><<<dim3(INNERC / 256, MROWS / 256), 512, 0, stream>>>(
        hid16, wbuf, projbuf, projbuf, MROWS, INNERC, DM);

    // output projection (f32 out) — overwrites X scratch in d_out
    cast_bf16_kernel<<<4096, 256, 0, stream>>>(w_out, wbuf, DM * INNERC);
    gemm256<2><<<dim3(DM / 256, MROWS / 256), 512, 0, stream>>>(
        projbuf, wbuf, d_out, nullptr, MROWS, DM, INNERC);
}